// Round 19
// baseline (122.126 us; speedup 1.0000x reference)
//
#include <hip/hip_runtime.h>
#include <math.h>

#define L_SEQ 256
#define TILE 16
#define NSEG 16

typedef __attribute__((ext_vector_type(2))) float f32x2;
typedef __attribute__((ext_vector_type(4))) float f32x4;
typedef __attribute__((ext_vector_type(8))) _Float16 f16x8;
typedef __attribute__((ext_vector_type(4))) _Float16 f16x4;
typedef __attribute__((ext_vector_type(2))) _Float16 f16x2;

__device__ __forceinline__ f32x2 fma2(f32x2 a, f32x2 b, f32x2 c) {
    return __builtin_elementwise_fma(a, b, c);
}
__device__ __forceinline__ f32x2 splat2(float x) { f32x2 v = {x, x}; return v; }
__device__ __forceinline__ float rcp_f(float x) {
#if __has_builtin(__builtin_amdgcn_rcpf)
    return __builtin_amdgcn_rcpf(x);
#else
    return 1.f / x;
#endif
}
__device__ __forceinline__ float silu_f(float x) { return x * rcp_f(1.f + __expf(-x)); }

// ---- prep (one launch, 7 blocks) ----
__global__ __launch_bounds__(256)
void k_prep(const float* __restrict__ exp_w, const float* __restrict__ exp_b,
            const float* __restrict__ in_proj_w, const float* __restrict__ x_proj_w,
            const float* __restrict__ dt_w,
            const float* __restrict__ conv_w, const float* __restrict__ conv_b,
            const float* __restrict__ A_log,
            _Float16* __restrict__ WT, _Float16* __restrict__ W2,
            float* __restrict__ bias2, int* __restrict__ sflag)
{
    const int t = threadIdx.x, blk = blockIdx.x;
    if (blk < 5) {
        const int base = blk * 4096;
        for (int i = base + t; i < base + 4096; i += 256) {
            const int row = i >> 7, k = i & 127;
            float v;
            if (row < 128) {
                v = x_proj_w[k * 36 + 0] * dt_w[row]
                  + x_proj_w[k * 36 + 1] * dt_w[128 + row]
                  + x_proj_w[k * 36 + 2] * dt_w[256 + row]
                  + x_proj_w[k * 36 + 3] * dt_w[384 + row];
            } else {
                v = x_proj_w[k * 36 + 4 + (row - 128)];
            }
            WT[i] = (_Float16)v;
        }
    } else if (blk == 5) {
        const int d = t & 127;
        const int col = (t < 128) ? d : (128 + d);
        float w0 = 0, w1 = 0, w2 = 0, w3 = 0, bb = 0;
        for (int k = 0; k < 64; ++k) {
            float w = in_proj_w[k * 256 + col];
            w0 = fmaf(exp_w[k], w, w0);
            w1 = fmaf(exp_w[64 + k], w, w1);
            w2 = fmaf(exp_w[128 + k], w, w2);
            w3 = fmaf(exp_w[192 + k], w, w3);
            bb = fmaf(exp_b[k], w, bb);
        }
        const float wx[4] = {w0, w1, w2, w3};
        if (t < 128) {
            for (int j = 0; j < 32; ++j) {
                float v = 0.f;
                if (j < 16)      v = conv_w[d * 4 + (j >> 2)] * wx[j & 3];
                else if (j < 20) v = conv_w[d * 4 + (j - 16)] * bb;
                W2[d * 32 + j] = (_Float16)v;
            }
            bias2[d] = conv_b[d];
        } else {
            for (int j = 0; j < 32; ++j) {
                float v = 0.f;
                if (j >= 12 && j < 16) v = wx[j - 12];
                else if (j == 19)      v = bb;
                W2[(128 + d) * 32 + j] = (_Float16)v;
            }
        }
    } else {
        __shared__ int ok;
        if (t == 0) ok = 1;
        __syncthreads();
        bool good = true;
        for (int i = t; i < 2048; i += 256) {
            float a = -__expf(A_log[i]);
            good = good && (fabsf(a + (float)((i & 15) + 1)) < 1e-3f);
        }
        if (!good) atomicAnd(&ok, 0);
        __syncthreads();
        if (t == 0) sflag[0] = ok;
    }
}

// ---- fused Mamba (unchanged from R17: proven ~95 us, VGPR 32, no spill) ----
__global__ __launch_bounds__(256, 8)
void mamba_seg(const float* __restrict__ reads,
               const _Float16* __restrict__ WT, const _Float16* __restrict__ W2,
               const float* __restrict__ bias2, const float* __restrict__ dt_b,
               const float* __restrict__ A_log, const float* __restrict__ D_skip,
               const int* __restrict__ sflag,
               f16x8* __restrict__ Qg8, f16x8* __restrict__ Pg8, f16x8* __restrict__ Kg8,
               float* __restrict__ Rg,
               float* __restrict__ GS, float* __restrict__ CZ, float* __restrict__ SL,
               int Bn)
{
    const int bx = blockIdx.x;
    const int b = bx >> 4, sidx = bx & 15;
    const int l_off = sidx * TILE;
    const int t = threadIdx.x;
    const int dd = t >> 1, g = t & 1;

    __shared__ __align__(16) _Float16 F[TILE * 40];
    __shared__ __align__(16) _Float16 XC[TILE * 136];
    __shared__ __align__(8)  f16x2    DR[TILE * 130];
    __shared__ _Float16               ZS[TILE * 132];
    __shared__ __align__(16) float    BC[TILE * 32];

    const float dskip = D_skip[dd];
    const bool structured = (sflag[0] != 0);

    for (int i = t; i < TILE * 40; i += 256) {
        const int l = i / 40, j = i - l * 40;
        _Float16 v = (_Float16)0.f;
        if (j < 16) {
            const int row = l_off + l - 3 + (j >> 2);
            if (row >= 0) v = (_Float16)reads[((size_t)b * L_SEQ + row) * 4 + (j & 3)];
        } else if (j < 20) {
            v = (l_off + l - 3 + (j - 16) >= 0) ? (_Float16)1.f : (_Float16)0.f;
        }
        F[i] = v;
    }
    __syncthreads();

    const int lane = t & 63, wv = t >> 6;
    const int fcol = lane & 15, kq = lane >> 4, rbase = kq * 4;

#pragma unroll
    for (int i = 0; i < 4; ++i) {
        const int n = wv + 4 * i;
        f16x8 af = *(const f16x8*)&F[fcol * 40 + kq * 8];
        f16x8 bf = *(const f16x8*)&W2[(n * 16 + fcol) * 32 + kq * 8];
        f32x4 acc = {0.f, 0.f, 0.f, 0.f};
        acc = __builtin_amdgcn_mfma_f32_16x16x32_f16(af, bf, acc, 0, 0, 0);
        if (n < 8) {
            const int ch = n * 16 + fcol;
            const float bv = bias2[ch];
#pragma unroll
            for (int r = 0; r < 4; ++r)
                XC[(rbase + r) * 136 + ch] = (_Float16)silu_f(acc[r] + bv);
        } else {
            const int ch = (n - 8) * 16 + fcol;
#pragma unroll
            for (int r = 0; r < 4; ++r)
                ZS[(rbase + r) * 132 + ch] = (_Float16)silu_f(acc[r]);
        }
    }
    __syncthreads();

#pragma unroll
    for (int i = 0; i < 3; ++i) {
        const int n = wv + 4 * i;
        if (n < 10) {
            f32x4 acc = {0.f, 0.f, 0.f, 0.f};
#pragma unroll
            for (int ks = 0; ks < 4; ++ks) {
                const int ko = ks * 32 + kq * 8;
                f16x8 xa = *(const f16x8*)&XC[fcol * 136 + ko];
                f16x8 bf = *(const f16x8*)&WT[(n * 16 + fcol) * 128 + ko];
                acc = __builtin_amdgcn_mfma_f32_16x16x32_f16(xa, bf, acc, 0, 0, 0);
            }
            if (n < 8) {
                const int ch = n * 16 + fcol;
                const float db = dt_b[ch];
#pragma unroll
                for (int r = 0; r < 4; ++r) {
                    const float dtr = fminf(acc[r] + db, 80.f);
                    const float ex = __expf(dtr);
                    const float opx = 1.f + ex;
                    const float de = __logf(opx);
                    const float rr = rcp_f(opx);
                    DR[(rbase + r) * 130 + ch] = (f16x2){(_Float16)de, (_Float16)rr};
                }
            } else {
                const int jb = (n - 8) * 16 + fcol;
#pragma unroll
                for (int r = 0; r < 4; ++r)
                    BC[(rbase + r) * 32 + jb] = acc[r];
            }
        }
    }
    __syncthreads();

    f32x2 h2[4], P2[4], K2[4];
#pragma unroll
    for (int k = 0; k < 4; ++k) { h2[k] = splat2(0.f); P2[k] = splat2(1.f); K2[k] = splat2(0.f); }
    f32x2 gs2 = splat2(0.f);
    float xz = 0.f;
    {
        auto scan_loop = [&](bool needpk) {
            for (int l = 0; l < TILE; ++l) {
                const f16x2 dz = DR[l * 130 + dd];
                const float de = (float)dz[0];
                const float rr = (float)dz[1];
                const float zs = (float)ZS[l * 132 + dd];
                const float xc = (float)XC[l * 136 + dd];
                const float du = de * xc;
                f32x2 E2[4];
                if (structured) {
                    const float r2 = rr * rr;
                    const float r4 = r2 * r2;
                    const float t1 = g ? (r4 * r4 * rr) : rr;
                    E2[0] = (f32x2){t1, t1 * rr};
                    const f32x2 r2s = splat2(r2);
                    E2[1] = E2[0] * r2s;
                    E2[2] = E2[1] * r2s;
                    E2[3] = E2[2] * r2s;
                } else {
#pragma unroll
                    for (int k = 0; k < 4; ++k) {
                        float e0 = exp2f(de * (-__expf(A_log[dd * 16 + g * 8 + 2 * k])) * 1.44269504f);
                        float e1 = exp2f(de * (-__expf(A_log[dd * 16 + g * 8 + 2 * k + 1])) * 1.44269504f);
                        E2[k] = (f32x2){e0, e1};
                    }
                }
                const float4 Bq0 = *(const float4*)&BC[l * 32 + g * 8];
                const float4 Bq1 = *(const float4*)&BC[l * 32 + g * 8 + 4];
                const float4 Cq0 = *(const float4*)&BC[l * 32 + 16 + g * 8];
                const float4 Cq1 = *(const float4*)&BC[l * 32 + 16 + g * 8 + 4];
                const f32x2 B2[4] = {{Bq0.x, Bq0.y}, {Bq0.z, Bq0.w}, {Bq1.x, Bq1.y}, {Bq1.z, Bq1.w}};
                const f32x2 C2[4] = {{Cq0.x, Cq0.y}, {Cq0.z, Cq0.w}, {Cq1.x, Cq1.y}, {Cq1.z, Cq1.w}};
                const f32x2 dus = splat2(du), zss = splat2(zs);
                f32x2 yp2 = splat2(0.f);
#pragma unroll
                for (int k = 0; k < 4; ++k) {
                    h2[k] = fma2(E2[k], h2[k], dus * B2[k]);
                    yp2 = fma2(h2[k], C2[k], yp2);
                    if (needpk) {
                        P2[k] = P2[k] * E2[k];
                        K2[k] = fma2(zss, C2[k] * P2[k], K2[k]);
                    }
                }
                gs2 = fma2(yp2, zss, gs2);
                xz = fmaf(xc, zs, xz);
            }
        };
        if (sidx == 0) scan_loop(false);
        else           scan_loop(true);
    }

    {
        const size_t sb = (size_t)sidx * Bn + b;
        const size_t rowq = (sb * 2 + g) * 128 + dd;
        f16x8 qv;
#pragma unroll
        for (int k = 0; k < 4; ++k) {
            qv[2 * k]     = (_Float16)h2[k].x;
            qv[2 * k + 1] = (_Float16)h2[k].y;
        }
        Qg8[rowq] = qv;
        if (sidx != 0) {
            f16x8 kv;
#pragma unroll
            for (int k = 0; k < 4; ++k) {
                kv[2 * k]     = (_Float16)K2[k].x;
                kv[2 * k + 1] = (_Float16)K2[k].y;
            }
            Kg8[rowq] = kv;
            if (structured) {
                if (g == 0) Rg[sb * 128 + dd] = P2[0].x;
            } else {
                f16x8 pv;
#pragma unroll
                for (int k = 0; k < 4; ++k) {
                    pv[2 * k]     = (_Float16)P2[k].x;
                    pv[2 * k + 1] = (_Float16)P2[k].y;
                }
                Pg8[rowq] = pv;
            }
        }
        float gsp = gs2.x + gs2.y;
        gsp += __shfl_xor(gsp, 1);
        const float gsum = fmaf(dskip, xz, gsp);
        if (g == 0) GS[sb * 128 + dd] = gsum;
        if (sidx == NSEG - 1) {
            const float zs_last = (float)ZS[(TILE - 1) * 132 + dd];
            const float xc_last = (float)XC[(TILE - 1) * 136 + dd];
#pragma unroll
            for (int k = 0; k < 8; ++k)
                CZ[((size_t)b * 16 + g * 8 + k) * 128 + dd] =
                    zs_last * BC[(TILE - 1) * 32 + 16 + g * 8 + k];
            if (g == 0) SL[(size_t)b * 128 + dd] = zs_last * xc_last * dskip;
        }
    }
}

// ---- stitch: R17 256-thread form; keysT now stored f16 ----
template<int NS>
__global__ __launch_bounds__(256)
void stitch(const f16x8* __restrict__ Qg8, const f16x8* __restrict__ Pg8,
            const f16x8* __restrict__ Kg8, const float* __restrict__ Rg,
            const float* __restrict__ GS,
            const float* __restrict__ CZ, const float* __restrict__ SL,
            const int* __restrict__ sflag,
            const float* __restrict__ out_proj_w,
            const float* __restrict__ k_w, const float* __restrict__ k_b,
            float* __restrict__ pooled, _Float16* __restrict__ keysTh, int Bn)
{
    const int b = blockIdx.x, t = threadIdx.x;
    const int d = t >> 1, g = t & 1;
    const bool structured = (sflag[0] != 0);
    __shared__ float gb[256];
    __shared__ float pl[128];

    float h[8];
    float gsum = (g == 0) ? GS[(size_t)b * 128 + d] : 0.f;
    {
        f16x8 qv = Qg8[((size_t)b * 2 + g) * 128 + d];
#pragma unroll
        for (int j = 0; j < 8; ++j) h[j] = (float)qv[j];
    }
#pragma unroll
    for (int s = 1; s < NS; ++s) {
        const size_t sb = (size_t)s * Bn + b;
        if (g == 0) gsum += GS[sb * 128 + d];
        const size_t rowq = (sb * 2 + g) * 128 + d;
        const f16x8 qv = Qg8[rowq];
        const f16x8 kv = Kg8[rowq];
        float P[8];
        if (structured) {
            const float R = Rg[sb * 128 + d];
            const float R2 = R * R;
            float t1 = R;
            if (g) { const float R4 = R2 * R2; t1 = R4 * R4 * R; }
            P[0] = t1;
#pragma unroll
            for (int j = 1; j < 8; ++j) P[j] = P[j - 1] * R;
        } else {
            const f16x8 pv = Pg8[rowq];
#pragma unroll
            for (int j = 0; j < 8; ++j) P[j] = (float)pv[j];
        }
        float corr = 0.f;
#pragma unroll
        for (int j = 0; j < 8; ++j) {
            corr = fmaf((float)kv[j], h[j], corr);
            h[j] = fmaf(P[j], h[j], (float)qv[j]);
        }
        gsum += corr;
    }
    float glast = (g == 0) ? SL[(size_t)b * 128 + d] : 0.f;
#pragma unroll
    for (int k = 0; k < 8; ++k)
        glast = fmaf(CZ[((size_t)b * 16 + g * 8 + k) * 128 + d], h[k], glast);

    gsum += __shfl_xor(gsum, 1);
    glast += __shfl_xor(glast, 1);
    if (g == 0) { gb[d] = gsum * (1.f / (float)L_SEQ); gb[128 + d] = glast; }
    __syncthreads();

    {
        const int oi = t >> 1;
        const int half = oi >> 6, oc = oi & 63;
        const float* gbp = &gb[half * 128];
        float s = 0.f;
#pragma unroll 16
        for (int i = g * 64; i < g * 64 + 64; ++i)
            s = fmaf(gbp[i], out_proj_w[i * 64 + oc], s);
        s += __shfl_xor(s, 1);
        if (g == 0) { pooled[(size_t)b * 128 + oi] = s; pl[oi] = s; }
    }
    __syncthreads();

    if (t < 128) {
        const int oc = t >> 1;
        float s = (g == 0) ? k_b[oc] : 0.f;
#pragma unroll 16
        for (int i = g * 64; i < g * 64 + 64; ++i)
            s = fmaf(pl[i], k_w[i * 64 + oc], s);
        s += __shfl_xor(s, 1);
        if (g == 0) keysTh[(size_t)oc * Bn + b] = (_Float16)s;
    }
}

// ---- qk: 4 queries per 256-thread block; f16 keysT (4x less L2 traffic) ----
__global__ __launch_bounds__(256)
void qk_kernel(const float* __restrict__ pooled, const int* __restrict__ idx,
               const float* __restrict__ q_w, const float* __restrict__ q_b,
               const _Float16* __restrict__ keysTh, float* __restrict__ out,
               int B, int N)
{
    const int n0 = blockIdx.x * 4, t = threadIdx.x;
    __shared__ float p[4][128];
    __shared__ float q[4][64];
    const int j = t >> 6, lt = t & 63;
    int nj = n0 + j; if (nj >= N) nj = N - 1;
    const int bij = idx[nj];
    *(float2*)&p[j][lt * 2] = *(const float2*)&pooled[(size_t)bij * 128 + lt * 2];
    __syncthreads();
    {
        float s = q_b[lt];
#pragma unroll
        for (int i = 0; i < 128; ++i) s = fmaf(p[j][i], q_w[i * 64 + lt], s);
        q[j][lt] = s;
    }
    __syncthreads();
    const int q2 = t >> 7;              // 0: queries 0,1 ; 1: queries 2,3
    const int m0 = (t & 127) * 4;
    f32x4 a0 = {0.f, 0.f, 0.f, 0.f}, a1 = {0.f, 0.f, 0.f, 0.f};
    const float* qA = q[2 * q2];
    const float* qB = q[2 * q2 + 1];
#pragma unroll 8
    for (int i = 0; i < 64; ++i) {
        const f16x4 kh = *(const f16x4*)&keysTh[(size_t)i * B + m0];
        const float k0 = (float)kh[0], k1 = (float)kh[1];
        const float k2 = (float)kh[2], k3 = (float)kh[3];
        const float qa = qA[i], qb_ = qB[i];
        a0[0] = fmaf(qa, k0, a0[0]); a0[1] = fmaf(qa, k1, a0[1]);
        a0[2] = fmaf(qa, k2, a0[2]); a0[3] = fmaf(qa, k3, a0[3]);
        a1[0] = fmaf(qb_, k0, a1[0]); a1[1] = fmaf(qb_, k1, a1[1]);
        a1[2] = fmaf(qb_, k2, a1[2]); a1[3] = fmaf(qb_, k3, a1[3]);
    }
    const int na = n0 + 2 * q2, nb = na + 1;
    if (na < N) *(f32x4*)&out[(size_t)na * B + m0] = a0;
    if (nb < N) *(f32x4*)&out[(size_t)nb * B + m0] = a1;
}

// ============================ LAUNCH ============================

extern "C" void kernel_launch(void* const* d_in, const int* in_sizes, int n_in,
                              void* d_out, int out_size, void* d_ws, size_t ws_size,
                              hipStream_t stream)
{
    const float* reads      = (const float*)d_in[0];
    const int*   idx        = (const int*)d_in[1];
    const float* exp_w      = (const float*)d_in[2];
    const float* exp_b      = (const float*)d_in[3];
    const float* in_proj_w  = (const float*)d_in[4];
    const float* conv_w     = (const float*)d_in[5];
    const float* conv_b     = (const float*)d_in[6];
    const float* x_proj_w   = (const float*)d_in[7];
    const float* dt_w       = (const float*)d_in[8];
    const float* dt_b       = (const float*)d_in[9];
    const float* A_log      = (const float*)d_in[10];
    const float* D_skip     = (const float*)d_in[11];
    const float* out_proj_w = (const float*)d_in[12];
    const float* q_w        = (const float*)d_in[13];
    const float* q_b        = (const float*)d_in[14];
    const float* k_w        = (const float*)d_in[15];
    const float* k_b        = (const float*)d_in[16];

    const int B = in_sizes[0] / (L_SEQ * 4);
    const int N = in_sizes[1];

    char* wsb = (char*)d_ws;
    size_t off = 0;
    auto alloc = [&](size_t bytes) {
        size_t o = off;
        off = (off + bytes + 255) & ~(size_t)255;
        return o;
    };

    float*     pooled = (float*)(wsb + alloc((size_t)B * 128 * 4));
    _Float16*  keysTh = (_Float16*)(wsb + alloc((size_t)B * 64 * 2));
    _Float16*  WT     = (_Float16*)(wsb + alloc(160 * 128 * 2));
    _Float16*  W2     = (_Float16*)(wsb + alloc(256 * 32 * 2));
    float*     bias2  = (float*)(wsb + alloc(128 * 4));
    int*       sflag  = (int*)(wsb + alloc(256));

    const size_t rows8 = (size_t)B * NSEG * 2 * 128;   // f16x8 elements
    f16x8* Qg8 = (f16x8*)(wsb + alloc(rows8 * 16));
    f16x8* Kg8 = (f16x8*)(wsb + alloc(rows8 * 16));
    f16x8* Pg8 = (f16x8*)(wsb + alloc(rows8 * 16));    // generic path only
    float* Rg  = (float*)Pg8;                          // alias: structured path only
    float* GS  = (float*)(wsb + alloc((size_t)B * NSEG * 128 * 4));
    float* CZ  = (float*)(wsb + alloc((size_t)B * 16 * 128 * 4));
    float* SL  = (float*)(wsb + alloc((size_t)B * 128 * 4));

    k_prep<<<7, 256, 0, stream>>>(exp_w, exp_b, in_proj_w, x_proj_w, dt_w,
                                  conv_w, conv_b, A_log, WT, W2, bias2, sflag);
    mamba_seg<<<B * NSEG, 256, 0, stream>>>(reads, WT, W2, bias2, dt_b,
                                            A_log, D_skip, sflag,
                                            Qg8, Pg8, Kg8, Rg,
                                            GS, CZ, SL, B);
    stitch<NSEG><<<B, 256, 0, stream>>>(Qg8, Pg8, Kg8, Rg, GS, CZ, SL, sflag,
                                        out_proj_w, k_w, k_b, pooled, keysTh, B);
    qk_kernel<<<(N + 3) / 4, 256, 0, stream>>>(pooled, idx, q_w, q_b, keysTh,
                                               (float*)d_out, B, N);
}